// Round 6
// baseline (3651.337 us; speedup 1.0000x reference)
//
#include <hip/hip_runtime.h>
#include <math.h>

#define NPTS 16384
#define NCTR 1024
#define BATCH 8

// Bit-exact squared distance matching numpy: ((dx*dx + dy*dy) + dz*dz),
// each op individually IEEE-rounded (no FMA contraction).
__device__ __forceinline__ float sq_dist(float x, float y, float z,
                                         float cx, float cy, float cz) {
  float dx = __fsub_rn(x, cx);
  float dy = __fsub_rn(y, cy);
  float dz = __fsub_rn(z, cz);
  return __fadd_rn(__fadd_rn(__fmul_rn(dx, dx), __fmul_rn(dy, dy)), __fmul_rn(dz, dz));
}

__device__ __forceinline__ float silu_f(float x) {
  return x / (1.0f + __expf(-x));
}

// 16 points per thread, named scalars. R2-R5 lesson: with 32 pts/thread
// (128 persistent floats) the allocator NEVER holds them — it settles at
// ~88 VGPRs and re-reads coords from cache every step (817MB FETCH),
// invariant under launch_bounds / waves_per_eu / asm pins. So shrink the
// persistent set to 64 floats (16 pts): required state now fits INSIDE the
// allocator's observed equilibrium, and waves_per_eu(4,4) (=1024 thr shape,
// 128-VGPR budget) agrees with it instead of fighting.
#define PT_LIST(F) \
  F(0)  F(1)  F(2)  F(3)  F(4)  F(5)  F(6)  F(7)  \
  F(8)  F(9)  F(10) F(11) F(12) F(13) F(14) F(15)

// ---------------------------------------------------------------------------
// Kernel 1: farthest point sampling. One block per batch, 1024 threads,
// 16 points/thread in named scalar registers. One barrier per step:
// wave argmax -> LDS (parity double-buffered, 16 slots) -> barrier ->
// redundant 16-way reduce in every thread -> centroid re-fetched from
// global via readfirstlane (uniform scalar load, L2-warm).
// Tie-break matches jnp.argmax first-occurrence: value desc, index asc.
// ---------------------------------------------------------------------------
__global__ __launch_bounds__(1024)
__attribute__((amdgpu_waves_per_eu(4, 4)))
void fps_kernel(const float* __restrict__ xyz, int* __restrict__ fps_idx) {
  const int b = blockIdx.x;
  const int t = threadIdx.x;
  const float* X = xyz + (size_t)b * 3 * NPTS;
  const float* Y = X + NPTS;
  const float* Z = X + 2 * NPTS;

#define DECL_PT(j) float px##j, py##j, pz##j, dist##j;
  PT_LIST(DECL_PT)
#undef DECL_PT

#define INIT_PT(j)                 \
  {                                \
    const int n = t + (j << 10);   \
    px##j = X[n];                  \
    py##j = Y[n];                  \
    pz##j = Z[n];                  \
    dist##j = __builtin_inff();    \
  }
  PT_LIST(INIT_PT)
#undef INIT_PT

  // Opaque pin: values can't be re-derived from memory.
#define PIN_PT(j) asm volatile("" : "+v"(px##j), "+v"(py##j), "+v"(pz##j));
  PT_LIST(PIN_PT)
#undef PIN_PT

  __shared__ float s_v[32];  // [parity][16 waves]
  __shared__ int s_n[32];
  const int w = t >> 6;
  const int lane = t & 63;

  if (t == 0) fps_idx[b * NCTR] = 0;
  // first centroid = point 0 (uniform broadcast load)
  float cx = X[0], cy = Y[0], cz = Z[0];

  for (int i = 1; i < NCTR; ++i) {
    float bv = -__builtin_inff();
    int bj = 0;
    // scan j ascending; strict > keeps the smallest j on ties
#define STEP_PT(j)                                            \
  {                                                           \
    const float d = sq_dist(px##j, py##j, pz##j, cx, cy, cz); \
    dist##j = fminf(dist##j, d);                              \
    const bool c = dist##j > bv;                              \
    bv = c ? dist##j : bv;                                    \
    bj = c ? j : bj;                                          \
  }
    PT_LIST(STEP_PT)
#undef STEP_PT
    int bn = (bj << 10) + t;  // global point index; n-order == (j,t) scan order

    // wave-level argmax, 64 lanes: value desc, index asc
#pragma unroll
    for (int off = 32; off >= 1; off >>= 1) {
      const float ov = __shfl_down(bv, off);
      const int on = __shfl_down(bn, off);
      if (ov > bv || (ov == bv && on < bn)) { bv = ov; bn = on; }
    }
    const int base = (i & 1) << 4;
    if (lane == 0) { s_v[base + w] = bv; s_n[base + w] = bn; }
    __syncthreads();  // the ONLY barrier per step

    // every thread redundantly reduces the 16 wave candidates (broadcast reads)
    float v0 = s_v[base + 0];
    int n0 = s_n[base + 0];
#pragma unroll
    for (int q = 1; q < 16; ++q) {
      const float vq = s_v[base + q];
      const int nq = s_n[base + q];
      if (vq > v0 || (vq == v0 && nq < n0)) { v0 = vq; n0 = nq; }
    }
    if (t == 0) fps_idx[b * NCTR + i] = n0;

    // all threads fetch winner coords from global (uniform -> scalar load)
    const int nu = __builtin_amdgcn_readfirstlane(n0);
    cx = X[nu];
    cy = Y[nu];
    cz = Z[nu];
  }
}

// ---------------------------------------------------------------------------
// Kernel 2: ball query. One wave per centroid; scan points in ascending index
// order, collect first 32 with dist <= r^2, pad with first hit.
// ---------------------------------------------------------------------------
__global__ __launch_bounds__(256) void ballq_kernel(const float* __restrict__ xyz,
                                                    const int* __restrict__ fps_idx,
                                                    int* __restrict__ ball_idx) {
  const int gw = (blockIdx.x * 256 + threadIdx.x) >> 6;  // 0..8191
  const int lane = threadIdx.x & 63;
  const int b = gw >> 10;
  const float* X = xyz + (size_t)b * 3 * NPTS;
  const float* Y = X + NPTS;
  const float* Z = X + 2 * NPTS;
  const int c = fps_idx[gw];
  const float cx = X[c], cy = Y[c], cz = Z[c];
  int* out = ball_idx + (size_t)gw * 32;
  const float R2 = 0.04f;

  int cnt = 0, first = -1;
  for (int base = 0; base < NPTS; base += 64) {
    const int j = base + lane;
    const float d = sq_dist(X[j], Y[j], Z[j], cx, cy, cz);
    const bool inb = !(d > R2);
    const unsigned long long m = __ballot(inb);
    if (first < 0 && m != 0ull) first = base + __ffsll(m) - 1;
    if (inb) {
      const int pos = cnt + __popcll(m & ((1ull << lane) - 1ull));
      if (pos < 32) out[pos] = j;
    }
    cnt += __popcll(m);
    if (cnt >= 32) break;
  }
  for (int k = cnt + lane; k < 32; k += 64) out[k] = first;
}

// ---------------------------------------------------------------------------
// Kernel 2b: one-off weight transpose into workspace: wt[c][o] layouts.
// ---------------------------------------------------------------------------
__global__ __launch_bounds__(256) void transpose_w_kernel(
    const float* __restrict__ w0, const float* __restrict__ w1,
    const float* __restrict__ w2, float* __restrict__ wt0,
    float* __restrict__ wt1, float* __restrict__ wt2) {
  const int t0 = blockIdx.x * 256 + threadIdx.x;
  const int stride = gridDim.x * 256;
  for (int e = t0; e < 64 * 67; e += stride) {
    int o = e / 67, c = e - o * 67;
    wt0[c * 64 + o] = w0[e];
  }
  for (int e = t0; e < 128 * 64; e += stride) {
    int o = e >> 6, c = e & 63;
    wt1[c * 128 + o] = w1[e];
  }
  for (int e = t0; e < 256 * 128; e += stride) {
    int o = e >> 7, c = e & 127;
    wt2[c * 256 + o] = w2[e];
  }
}

// ---------------------------------------------------------------------------
// Kernel 3: fused gather + 3-layer pointwise MLP + mean over 32 samples.
// One block per (b, s) group, 256 threads. Activations LDS channel-major
// [c][36] (float4 over k); weights staged from pre-transposed wt* with
// stride-1 conflict-free LDS writes.
// ---------------------------------------------------------------------------
__global__ __launch_bounds__(256, 2) void mlp_kernel(
    const float* __restrict__ xyz, const float* __restrict__ points,
    const int* __restrict__ fps_idx, const int* __restrict__ ball_idx,
    const float* __restrict__ wt0, const float* __restrict__ b0,
    const float* __restrict__ wt1, const float* __restrict__ b1,
    const float* __restrict__ wt2, const float* __restrict__ b2,
    float* __restrict__ out) {
  const int s = blockIdx.x, b = blockIdx.y, t = threadIdx.x;

  __shared__ float A1[64 * 36];    // layer0 out [o][k]
  __shared__ float A2[128 * 36];   // layer1 out [o][k]
  __shared__ float S[8704];        // scratch: A0+Wt0 | Wt1 | Wt2 chunk
  __shared__ float bias_sh[256];
  __shared__ int jidx[32];
  __shared__ float ctr[3];

  const int g = b * NCTR + s;

  // phase 1: indices, centroid, Wt0 [67][68] (stride-1 writes), bias0
  if (t < 32) jidx[t] = ball_idx[(size_t)g * 32 + t];
  if (t < 3) ctr[t] = xyz[((size_t)b * 3 + t) * NPTS + fps_idx[g]];
  float* A0 = S;              // [67][36]
  float* Wt0 = S + 67 * 36;   // [67][68]
  for (int e = t; e < 67 * 64; e += 256) {
    int c = e >> 6, o = e & 63;
    Wt0[c * 68 + o] = wt0[e];  // global coalesced, LDS stride-1
  }
  if (t < 64) bias_sh[t] = b0[t];
  __syncthreads();

  // phase 2: gather A0 = [xyz_norm(3); points(64)] x 32 samples
  for (int e = t; e < 67 * 32; e += 256) {
    int c = e >> 5, k = e & 31;
    int j = jidx[k];
    float v;
    if (c < 3)
      v = xyz[((size_t)b * 3 + c) * NPTS + j] - ctr[c];
    else
      v = points[((size_t)b * 64 + (c - 3)) * NPTS + j];
    A0[c * 36 + k] = v;
  }
  __syncthreads();

  // phase 3: layer 0 (67 -> 64), tile 4k x 2o
  {
    const int o0 = (t & 31) * 2;
    const int k0 = (t >> 5) * 4;
    float acc[4][2] = {{0.f, 0.f}, {0.f, 0.f}, {0.f, 0.f}, {0.f, 0.f}};
    for (int c = 0; c < 67; ++c) {
      const float4 a = *(const float4*)(A0 + c * 36 + k0);
      const float wv0 = Wt0[c * 68 + o0];
      const float wv1 = Wt0[c * 68 + o0 + 1];
      acc[0][0] = fmaf(a.x, wv0, acc[0][0]);
      acc[1][0] = fmaf(a.y, wv0, acc[1][0]);
      acc[2][0] = fmaf(a.z, wv0, acc[2][0]);
      acc[3][0] = fmaf(a.w, wv0, acc[3][0]);
      acc[0][1] = fmaf(a.x, wv1, acc[0][1]);
      acc[1][1] = fmaf(a.y, wv1, acc[1][1]);
      acc[2][1] = fmaf(a.z, wv1, acc[2][1]);
      acc[3][1] = fmaf(a.w, wv1, acc[3][1]);
    }
#pragma unroll
    for (int i = 0; i < 2; ++i) {
      const float bb = bias_sh[o0 + i];
      float4 r;
      r.x = silu_f(acc[0][i] + bb);
      r.y = silu_f(acc[1][i] + bb);
      r.z = silu_f(acc[2][i] + bb);
      r.w = silu_f(acc[3][i] + bb);
      *(float4*)(A1 + (o0 + i) * 36 + k0) = r;
    }
  }
  __syncthreads();

  // phase 4: stage Wt1 [64][132] (stride-1 writes), bias1
  float* Wt1 = S;
  for (int e = t; e < 128 * 64; e += 256) {
    int c = e >> 7, o = e & 127;
    Wt1[c * 132 + o] = wt1[e];
  }
  if (t < 128) bias_sh[t] = b1[t];
  __syncthreads();

  // phase 5: layer 1 (64 -> 128), tile 4k x 4o
  {
    const int o0 = (t & 31) * 4;
    const int k0 = (t >> 5) * 4;
    float acc[4][4];
#pragma unroll
    for (int kk = 0; kk < 4; ++kk)
#pragma unroll
      for (int oo = 0; oo < 4; ++oo) acc[kk][oo] = 0.f;
    for (int c = 0; c < 64; ++c) {
      const float4 a = *(const float4*)(A1 + c * 36 + k0);
      const float4 w = *(const float4*)(Wt1 + c * 132 + o0);
      const float av[4] = {a.x, a.y, a.z, a.w};
      const float wv[4] = {w.x, w.y, w.z, w.w};
#pragma unroll
      for (int kk = 0; kk < 4; ++kk)
#pragma unroll
        for (int oo = 0; oo < 4; ++oo)
          acc[kk][oo] = fmaf(av[kk], wv[oo], acc[kk][oo]);
    }
#pragma unroll
    for (int oo = 0; oo < 4; ++oo) {
      const float bb = bias_sh[o0 + oo];
      float4 r;
      r.x = silu_f(acc[0][oo] + bb);
      r.y = silu_f(acc[1][oo] + bb);
      r.z = silu_f(acc[2][oo] + bb);
      r.w = silu_f(acc[3][oo] + bb);
      *(float4*)(A2 + (o0 + oo) * 36 + k0) = r;
    }
  }
  __syncthreads();

  // phase 6: layer 2 (128 -> 256) in 4 chunks of 64 outputs + mean over k
  float* Wt2 = S;   // [128][68] per chunk
  float* P = A1;    // partial sums [64][9] (A1 dead)
  const int o0 = (t & 31) * 2;
  const int k0 = (t >> 5) * 4;
  const int kg = t >> 5;
  for (int chunk = 0; chunk < 4; ++chunk) {
    for (int e = t; e < 64 * 128; e += 256) {
      int c = e >> 6, o = e & 63;
      Wt2[c * 68 + o] = wt2[c * 256 + chunk * 64 + o];  // coalesced / stride-1
    }
    if (t < 64) bias_sh[t] = b2[chunk * 64 + t];
    __syncthreads();

    float acc[4][2] = {{0.f, 0.f}, {0.f, 0.f}, {0.f, 0.f}, {0.f, 0.f}};
    for (int c = 0; c < 128; ++c) {
      const float4 a = *(const float4*)(A2 + c * 36 + k0);
      const float wv0 = Wt2[c * 68 + o0];
      const float wv1 = Wt2[c * 68 + o0 + 1];
      acc[0][0] = fmaf(a.x, wv0, acc[0][0]);
      acc[1][0] = fmaf(a.y, wv0, acc[1][0]);
      acc[2][0] = fmaf(a.z, wv0, acc[2][0]);
      acc[3][0] = fmaf(a.w, wv0, acc[3][0]);
      acc[0][1] = fmaf(a.x, wv1, acc[0][1]);
      acc[1][1] = fmaf(a.y, wv1, acc[1][1]);
      acc[2][1] = fmaf(a.z, wv1, acc[2][1]);
      acc[3][1] = fmaf(a.w, wv1, acc[3][1]);
    }
#pragma unroll
    for (int i = 0; i < 2; ++i) {
      const float bb = bias_sh[o0 + i];
      float sum = silu_f(acc[0][i] + bb) + silu_f(acc[1][i] + bb) +
                  silu_f(acc[2][i] + bb) + silu_f(acc[3][i] + bb);
      P[(o0 + i) * 9 + kg] = sum;
    }
    __syncthreads();
    if (t < 64) {
      float tot = 0.f;
#pragma unroll
      for (int q = 0; q < 8; ++q) tot += P[t * 9 + q];
      out[((size_t)b * 256 + chunk * 64 + t) * NCTR + s] = tot * (1.0f / 32.0f);
    }
    __syncthreads();
  }
}

extern "C" void kernel_launch(void* const* d_in, const int* in_sizes, int n_in,
                              void* d_out, int out_size, void* d_ws, size_t ws_size,
                              hipStream_t stream) {
  const float* xyz = (const float*)d_in[0];
  const float* points = (const float*)d_in[1];
  const float* w0 = (const float*)d_in[2];
  const float* b0 = (const float*)d_in[3];
  const float* w1 = (const float*)d_in[4];
  const float* b1 = (const float*)d_in[5];
  const float* w2 = (const float*)d_in[6];
  const float* b2 = (const float*)d_in[7];
  float* out = (float*)d_out;

  int* fps = (int*)d_ws;           // 8*1024 ints
  int* bidx = (int*)d_ws + 8192;   // 8*1024*32 ints
  float* wt0 = (float*)d_ws + 270336;         // 67*64
  float* wt1 = wt0 + 67 * 64;                 // 64*128
  float* wt2 = wt1 + 64 * 128;                // 128*256  (total ws ~1.27 MB)

  transpose_w_kernel<<<64, 256, 0, stream>>>(w0, w1, w2, wt0, wt1, wt2);
  fps_kernel<<<BATCH, 1024, 0, stream>>>(xyz, fps);
  ballq_kernel<<<2048, 256, 0, stream>>>(xyz, fps, bidx);
  mlp_kernel<<<dim3(NCTR, BATCH), 256, 0, stream>>>(xyz, points, fps, bidx,
                                                    wt0, b0, wt1, b1, wt2, b2, out);
}

// Round 7
// 3109.269 us; speedup vs baseline: 1.1743x; 1.1743x over previous
//
#include <hip/hip_runtime.h>
#include <math.h>

#define NPTS 16384
#define NCTR 1024
#define BATCH 8

// Bit-exact squared distance matching numpy: ((dx*dx + dy*dy) + dz*dz),
// each op individually IEEE-rounded (no FMA contraction).
__device__ __forceinline__ float sq_dist(float x, float y, float z,
                                         float cx, float cy, float cz) {
  float dx = __fsub_rn(x, cx);
  float dy = __fsub_rn(y, cy);
  float dz = __fsub_rn(z, cz);
  return __fadd_rn(__fadd_rn(__fmul_rn(dx, dx), __fmul_rn(dy, dy)), __fmul_rn(dz, dz));
}

__device__ __forceinline__ float silu_f(float x) {
  return x / (1.0f + __expf(-x));
}

// ---------------------------------------------------------------------------
// Kernel 1: farthest point sampling. One block per batch, 1024 threads.
// R6 post-mortem (units corrected): FETCH_SIZE was ~820 KB not MB — FPS has
// ~no HBM traffic. The compiler's equilibrium re-reads all coords from L2
// every step (192 KB/step/block ≈ 3500 cyc at ~56 B/cyc/CU) — FPS is
// L2-BW-bound. Fix: x,y arrays in LDS (128 KB), z + dist as 32 named
// scalars/thread. 128 KB LDS pins occupancy to 1 block/CU at compile time,
// so the RA's occupancy target finally matches the layout.
// One barrier per step: wave argmax -> LDS (parity double-buffered, 16
// slots) -> barrier -> 16-lane mini wave-reduce (every wave, lane0 result)
// -> centroid x,y from LDS broadcast read, z from global uniform load.
// Tie-break matches jnp.argmax first-occurrence: value desc, index asc.
// ---------------------------------------------------------------------------
#define CH_LIST(F) F(0) F(1) F(2) F(3)

__global__ __launch_bounds__(1024)
void fps_kernel(const float* __restrict__ xyz, int* __restrict__ fps_idx) {
  const int b = blockIdx.x;
  const int t = threadIdx.x;
  const float* X = xyz + (size_t)b * 3 * NPTS;
  const float* Y = X + NPTS;
  const float* Z = X + 2 * NPTS;

  __shared__ float sx[NPTS];   // 64 KB
  __shared__ float sy[NPTS];   // 64 KB
  __shared__ float s_v[32];    // [parity][16 waves]
  __shared__ int s_n[32];

  // 16 points/thread as 4 chunks of 4 consecutive points:
  // chunk c covers p = (c<<12) + 4*t + {0,1,2,3}
#define DECL_CH(c) float z0##c, z1##c, z2##c, z3##c, d0##c, d1##c, d2##c, d3##c;
  CH_LIST(DECL_CH)
#undef DECL_CH

#define INIT_CH(c)                                   \
  {                                                  \
    const int p = (c << 12) + (t << 2);              \
    *(float4*)(sx + p) = *(const float4*)(X + p);    \
    *(float4*)(sy + p) = *(const float4*)(Y + p);    \
    const float4 zq = *(const float4*)(Z + p);       \
    z0##c = zq.x; z1##c = zq.y;                      \
    z2##c = zq.z; z3##c = zq.w;                      \
    d0##c = __builtin_inff(); d1##c = __builtin_inff(); \
    d2##c = __builtin_inff(); d3##c = __builtin_inff(); \
  }
  CH_LIST(INIT_CH)
#undef INIT_CH

  // pin z coords so they can't be re-derived from memory
#define PIN_CH(c) asm volatile("" : "+v"(z0##c), "+v"(z1##c), "+v"(z2##c), "+v"(z3##c));
  CH_LIST(PIN_CH)
#undef PIN_CH

  const int w = t >> 6;
  const int lane = t & 63;

  if (t == 0) fps_idx[b * NCTR] = 0;
  __syncthreads();  // LDS staging complete
  float cx = sx[0], cy = sy[0], cz = Z[0];

  for (int i = 1; i < NCTR; ++i) {
    float bv = -__builtin_inff();
    int bp = 0;
    // within-thread scan in ascending p; strict > keeps the earliest index
#define STEP_CH(c)                                                     \
  {                                                                    \
    const int p = (c << 12) + (t << 2);                                \
    const float4 xq = *(const float4*)(sx + p);                        \
    const float4 yq = *(const float4*)(sy + p);                        \
    float d;                                                           \
    d = sq_dist(xq.x, yq.x, z0##c, cx, cy, cz);                        \
    d0##c = fminf(d0##c, d);                                           \
    if (d0##c > bv) { bv = d0##c; bp = p; }                            \
    d = sq_dist(xq.y, yq.y, z1##c, cx, cy, cz);                        \
    d1##c = fminf(d1##c, d);                                           \
    if (d1##c > bv) { bv = d1##c; bp = p + 1; }                        \
    d = sq_dist(xq.z, yq.z, z2##c, cx, cy, cz);                        \
    d2##c = fminf(d2##c, d);                                           \
    if (d2##c > bv) { bv = d2##c; bp = p + 2; }                        \
    d = sq_dist(xq.w, yq.w, z3##c, cx, cy, cz);                        \
    d3##c = fminf(d3##c, d);                                           \
    if (d3##c > bv) { bv = d3##c; bp = p + 3; }                        \
  }
    CH_LIST(STEP_CH)
#undef STEP_CH

    // wave-level argmax, 64 lanes: value desc, index asc
#pragma unroll
    for (int off = 32; off >= 1; off >>= 1) {
      const float ov = __shfl_down(bv, off);
      const int op = __shfl_down(bp, off);
      if (ov > bv || (ov == bv && op < bp)) { bv = ov; bp = op; }
    }
    const int base = (i & 1) << 4;
    if (lane == 0) { s_v[base + w] = bv; s_n[base + w] = bp; }
    __syncthreads();  // the ONLY barrier per step

    // 16-slot mini-reduce done redundantly by every wave (lanes 16+ mirror
    // lanes 0-15 via broadcast reads; lane 0 of each wave ends correct)
    const int sl = base + (lane & 15);
    float v = s_v[sl];
    int n = s_n[sl];
#pragma unroll
    for (int off = 8; off >= 1; off >>= 1) {
      const float ov = __shfl_down(v, off);
      const int on = __shfl_down(n, off);
      if (ov > v || (ov == v && on < n)) { v = ov; n = on; }
    }
    const int nu = __builtin_amdgcn_readfirstlane(n);
    if (t == 0) fps_idx[b * NCTR + i] = nu;

    // centroid: x,y from LDS broadcast, z from global uniform load
    cx = sx[nu];
    cy = sy[nu];
    cz = Z[nu];
  }
}

// ---------------------------------------------------------------------------
// Kernel 2: ball query. One wave per centroid; scan points in ascending index
// order, collect first 32 with dist <= r^2, pad with first hit.
// ---------------------------------------------------------------------------
__global__ __launch_bounds__(256) void ballq_kernel(const float* __restrict__ xyz,
                                                    const int* __restrict__ fps_idx,
                                                    int* __restrict__ ball_idx) {
  const int gw = (blockIdx.x * 256 + threadIdx.x) >> 6;  // 0..8191
  const int lane = threadIdx.x & 63;
  const int b = gw >> 10;
  const float* X = xyz + (size_t)b * 3 * NPTS;
  const float* Y = X + NPTS;
  const float* Z = X + 2 * NPTS;
  const int c = fps_idx[gw];
  const float cx = X[c], cy = Y[c], cz = Z[c];
  int* out = ball_idx + (size_t)gw * 32;
  const float R2 = 0.04f;

  int cnt = 0, first = -1;
  for (int base = 0; base < NPTS; base += 64) {
    const int j = base + lane;
    const float d = sq_dist(X[j], Y[j], Z[j], cx, cy, cz);
    const bool inb = !(d > R2);
    const unsigned long long m = __ballot(inb);
    if (first < 0 && m != 0ull) first = base + __ffsll(m) - 1;
    if (inb) {
      const int pos = cnt + __popcll(m & ((1ull << lane) - 1ull));
      if (pos < 32) out[pos] = j;
    }
    cnt += __popcll(m);
    if (cnt >= 32) break;
  }
  for (int k = cnt + lane; k < 32; k += 64) out[k] = first;
}

// ---------------------------------------------------------------------------
// Kernel 2b: one-off weight transpose into workspace: wt[c][o] layouts.
// ---------------------------------------------------------------------------
__global__ __launch_bounds__(256) void transpose_w_kernel(
    const float* __restrict__ w0, const float* __restrict__ w1,
    const float* __restrict__ w2, float* __restrict__ wt0,
    float* __restrict__ wt1, float* __restrict__ wt2) {
  const int t0 = blockIdx.x * 256 + threadIdx.x;
  const int stride = gridDim.x * 256;
  for (int e = t0; e < 64 * 67; e += stride) {
    int o = e / 67, c = e - o * 67;
    wt0[c * 64 + o] = w0[e];
  }
  for (int e = t0; e < 128 * 64; e += stride) {
    int o = e >> 6, c = e & 63;
    wt1[c * 128 + o] = w1[e];
  }
  for (int e = t0; e < 256 * 128; e += stride) {
    int o = e >> 7, c = e & 127;
    wt2[c * 256 + o] = w2[e];
  }
}

// ---------------------------------------------------------------------------
// Kernel 3: fused gather + 3-layer pointwise MLP + mean over 32 samples.
// One block per (b, s) group, 256 threads. Activations LDS channel-major
// [c][36] (float4 over k); weights staged from pre-transposed wt* with
// stride-1 conflict-free LDS writes.
// ---------------------------------------------------------------------------
__global__ __launch_bounds__(256, 2) void mlp_kernel(
    const float* __restrict__ xyz, const float* __restrict__ points,
    const int* __restrict__ fps_idx, const int* __restrict__ ball_idx,
    const float* __restrict__ wt0, const float* __restrict__ b0,
    const float* __restrict__ wt1, const float* __restrict__ b1,
    const float* __restrict__ wt2, const float* __restrict__ b2,
    float* __restrict__ out) {
  const int s = blockIdx.x, b = blockIdx.y, t = threadIdx.x;

  __shared__ float A1[64 * 36];    // layer0 out [o][k]
  __shared__ float A2[128 * 36];   // layer1 out [o][k]
  __shared__ float S[8704];        // scratch: A0+Wt0 | Wt1 | Wt2 chunk
  __shared__ float bias_sh[256];
  __shared__ int jidx[32];
  __shared__ float ctr[3];

  const int g = b * NCTR + s;

  // phase 1: indices, centroid, Wt0 [67][68] (stride-1 writes), bias0
  if (t < 32) jidx[t] = ball_idx[(size_t)g * 32 + t];
  if (t < 3) ctr[t] = xyz[((size_t)b * 3 + t) * NPTS + fps_idx[g]];
  float* A0 = S;              // [67][36]
  float* Wt0 = S + 67 * 36;   // [67][68]
  for (int e = t; e < 67 * 64; e += 256) {
    int c = e >> 6, o = e & 63;
    Wt0[c * 68 + o] = wt0[e];  // global coalesced, LDS stride-1
  }
  if (t < 64) bias_sh[t] = b0[t];
  __syncthreads();

  // phase 2: gather A0 = [xyz_norm(3); points(64)] x 32 samples
  for (int e = t; e < 67 * 32; e += 256) {
    int c = e >> 5, k = e & 31;
    int j = jidx[k];
    float v;
    if (c < 3)
      v = xyz[((size_t)b * 3 + c) * NPTS + j] - ctr[c];
    else
      v = points[((size_t)b * 64 + (c - 3)) * NPTS + j];
    A0[c * 36 + k] = v;
  }
  __syncthreads();

  // phase 3: layer 0 (67 -> 64), tile 4k x 2o
  {
    const int o0 = (t & 31) * 2;
    const int k0 = (t >> 5) * 4;
    float acc[4][2] = {{0.f, 0.f}, {0.f, 0.f}, {0.f, 0.f}, {0.f, 0.f}};
    for (int c = 0; c < 67; ++c) {
      const float4 a = *(const float4*)(A0 + c * 36 + k0);
      const float wv0 = Wt0[c * 68 + o0];
      const float wv1 = Wt0[c * 68 + o0 + 1];
      acc[0][0] = fmaf(a.x, wv0, acc[0][0]);
      acc[1][0] = fmaf(a.y, wv0, acc[1][0]);
      acc[2][0] = fmaf(a.z, wv0, acc[2][0]);
      acc[3][0] = fmaf(a.w, wv0, acc[3][0]);
      acc[0][1] = fmaf(a.x, wv1, acc[0][1]);
      acc[1][1] = fmaf(a.y, wv1, acc[1][1]);
      acc[2][1] = fmaf(a.z, wv1, acc[2][1]);
      acc[3][1] = fmaf(a.w, wv1, acc[3][1]);
    }
#pragma unroll
    for (int i = 0; i < 2; ++i) {
      const float bb = bias_sh[o0 + i];
      float4 r;
      r.x = silu_f(acc[0][i] + bb);
      r.y = silu_f(acc[1][i] + bb);
      r.z = silu_f(acc[2][i] + bb);
      r.w = silu_f(acc[3][i] + bb);
      *(float4*)(A1 + (o0 + i) * 36 + k0) = r;
    }
  }
  __syncthreads();

  // phase 4: stage Wt1 [64][132] (stride-1 writes), bias1
  float* Wt1 = S;
  for (int e = t; e < 128 * 64; e += 256) {
    int c = e >> 7, o = e & 127;
    Wt1[c * 132 + o] = wt1[e];
  }
  if (t < 128) bias_sh[t] = b1[t];
  __syncthreads();

  // phase 5: layer 1 (64 -> 128), tile 4k x 4o
  {
    const int o0 = (t & 31) * 4;
    const int k0 = (t >> 5) * 4;
    float acc[4][4];
#pragma unroll
    for (int kk = 0; kk < 4; ++kk)
#pragma unroll
      for (int oo = 0; oo < 4; ++oo) acc[kk][oo] = 0.f;
    for (int c = 0; c < 64; ++c) {
      const float4 a = *(const float4*)(A1 + c * 36 + k0);
      const float4 w = *(const float4*)(Wt1 + c * 132 + o0);
      const float av[4] = {a.x, a.y, a.z, a.w};
      const float wv[4] = {w.x, w.y, w.z, w.w};
#pragma unroll
      for (int kk = 0; kk < 4; ++kk)
#pragma unroll
        for (int oo = 0; oo < 4; ++oo)
          acc[kk][oo] = fmaf(av[kk], wv[oo], acc[kk][oo]);
    }
#pragma unroll
    for (int oo = 0; oo < 4; ++oo) {
      const float bb = bias_sh[o0 + oo];
      float4 r;
      r.x = silu_f(acc[0][oo] + bb);
      r.y = silu_f(acc[1][oo] + bb);
      r.z = silu_f(acc[2][oo] + bb);
      r.w = silu_f(acc[3][oo] + bb);
      *(float4*)(A2 + (o0 + oo) * 36 + k0) = r;
    }
  }
  __syncthreads();

  // phase 6: layer 2 (128 -> 256) in 4 chunks of 64 outputs + mean over k
  float* Wt2 = S;   // [128][68] per chunk
  float* P = A1;    // partial sums [64][9] (A1 dead)
  const int o0 = (t & 31) * 2;
  const int k0 = (t >> 5) * 4;
  const int kg = t >> 5;
  for (int chunk = 0; chunk < 4; ++chunk) {
    for (int e = t; e < 64 * 128; e += 256) {
      int c = e >> 6, o = e & 63;
      Wt2[c * 68 + o] = wt2[c * 256 + chunk * 64 + o];  // coalesced / stride-1
    }
    if (t < 64) bias_sh[t] = b2[chunk * 64 + t];
    __syncthreads();

    float acc[4][2] = {{0.f, 0.f}, {0.f, 0.f}, {0.f, 0.f}, {0.f, 0.f}};
    for (int c = 0; c < 128; ++c) {
      const float4 a = *(const float4*)(A2 + c * 36 + k0);
      const float wv0 = Wt2[c * 68 + o0];
      const float wv1 = Wt2[c * 68 + o0 + 1];
      acc[0][0] = fmaf(a.x, wv0, acc[0][0]);
      acc[1][0] = fmaf(a.y, wv0, acc[1][0]);
      acc[2][0] = fmaf(a.z, wv0, acc[2][0]);
      acc[3][0] = fmaf(a.w, wv0, acc[3][0]);
      acc[0][1] = fmaf(a.x, wv1, acc[0][1]);
      acc[1][1] = fmaf(a.y, wv1, acc[1][1]);
      acc[2][1] = fmaf(a.z, wv1, acc[2][1]);
      acc[3][1] = fmaf(a.w, wv1, acc[3][1]);
    }
#pragma unroll
    for (int i = 0; i < 2; ++i) {
      const float bb = bias_sh[o0 + i];
      float sum = silu_f(acc[0][i] + bb) + silu_f(acc[1][i] + bb) +
                  silu_f(acc[2][i] + bb) + silu_f(acc[3][i] + bb);
      P[(o0 + i) * 9 + kg] = sum;
    }
    __syncthreads();
    if (t < 64) {
      float tot = 0.f;
#pragma unroll
      for (int q = 0; q < 8; ++q) tot += P[t * 9 + q];
      out[((size_t)b * 256 + chunk * 64 + t) * NCTR + s] = tot * (1.0f / 32.0f);
    }
    __syncthreads();
  }
}

extern "C" void kernel_launch(void* const* d_in, const int* in_sizes, int n_in,
                              void* d_out, int out_size, void* d_ws, size_t ws_size,
                              hipStream_t stream) {
  const float* xyz = (const float*)d_in[0];
  const float* points = (const float*)d_in[1];
  const float* w0 = (const float*)d_in[2];
  const float* b0 = (const float*)d_in[3];
  const float* w1 = (const float*)d_in[4];
  const float* b1 = (const float*)d_in[5];
  const float* w2 = (const float*)d_in[6];
  const float* b2 = (const float*)d_in[7];
  float* out = (float*)d_out;

  int* fps = (int*)d_ws;           // 8*1024 ints
  int* bidx = (int*)d_ws + 8192;   // 8*1024*32 ints
  float* wt0 = (float*)d_ws + 270336;         // 67*64
  float* wt1 = wt0 + 67 * 64;                 // 64*128
  float* wt2 = wt1 + 64 * 128;                // 128*256  (total ws ~1.27 MB)

  transpose_w_kernel<<<64, 256, 0, stream>>>(w0, w1, w2, wt0, wt1, wt2);
  fps_kernel<<<BATCH, 1024, 0, stream>>>(xyz, fps);
  ballq_kernel<<<2048, 256, 0, stream>>>(xyz, fps, bidx);
  mlp_kernel<<<dim3(NCTR, BATCH), 256, 0, stream>>>(xyz, points, fps, bidx,
                                                    wt0, b0, wt1, b1, wt2, b2, out);
}

// Round 8
// 2965.055 us; speedup vs baseline: 1.2315x; 1.0486x over previous
//
#include <hip/hip_runtime.h>
#include <math.h>

#define NPTS 16384
#define NCTR 1024
#define BATCH 8
#define NCELL 512  // 8x8x8 Morton cells

// Bit-exact squared distance matching numpy: ((dx*dx + dy*dy) + dz*dz),
// each op individually IEEE-rounded (no FMA contraction).
__device__ __forceinline__ float sq_dist(float x, float y, float z,
                                         float cx, float cy, float cz) {
  float dx = __fsub_rn(x, cx);
  float dy = __fsub_rn(y, cy);
  float dz = __fsub_rn(z, cz);
  return __fadd_rn(__fadd_rn(__fmul_rn(dx, dx), __fmul_rn(dy, dy)), __fmul_rn(dz, dz));
}

__device__ __forceinline__ float silu_f(float x) {
  return x / (1.0f + __expf(-x));
}

__device__ __forceinline__ int morton_cell(float x, float y, float z) {
  int mx = min(7, max(0, (int)(x * 8.0f)));
  int my = min(7, max(0, (int)(y * 8.0f)));
  int mz = min(7, max(0, (int)(z * 8.0f)));
  int m = 0;
#pragma unroll
  for (int k = 0; k < 3; ++k) {
    m |= ((mx >> k) & 1) << (3 * k + 2);
    m |= ((my >> k) & 1) << (3 * k + 1);
    m |= ((mz >> k) & 1) << (3 * k + 0);
  }
  return m;
}

// ---------------------------------------------------------------------------
// Kernel 0: Morton counting sort, one block per batch. Order within a cell is
// atomic-race order — harmless: all downstream argmax logic compares
// (value desc, ORIG index asc), which is order-invariant and exactly matches
// jnp.argmax first-occurrence semantics.
// ---------------------------------------------------------------------------
__global__ __launch_bounds__(1024) void sort_kernel(
    const float* __restrict__ xyz, float* __restrict__ sxg,
    float* __restrict__ syg, float* __restrict__ szg, int* __restrict__ sog) {
  const int b = blockIdx.x, t = threadIdx.x;
  const float* X = xyz + (size_t)b * 3 * NPTS;
  const float* Y = X + NPTS;
  const float* Z = X + 2 * NPTS;
  __shared__ int cnt[NCELL];
  __shared__ int off[NCELL];
  for (int e = t; e < NCELL; e += 1024) cnt[e] = 0;
  __syncthreads();
#pragma unroll
  for (int j = 0; j < 16; ++j) {
    const int n = t + (j << 10);
    atomicAdd(&cnt[morton_cell(X[n], Y[n], Z[n])], 1);
  }
  __syncthreads();
  if (t < NCELL) off[t] = cnt[t];
  __syncthreads();
  for (int d = 1; d < NCELL; d <<= 1) {  // inclusive Hillis-Steele scan
    int v = 0;
    if (t < NCELL) { v = off[t]; if (t >= d) v += off[t - d]; }
    __syncthreads();
    if (t < NCELL) off[t] = v;
    __syncthreads();
  }
  if (t < NCELL) off[t] -= cnt[t];  // exclusive starts / running allocator
  __syncthreads();
  float* sx = sxg + (size_t)b * NPTS;
  float* sy = syg + (size_t)b * NPTS;
  float* sz = szg + (size_t)b * NPTS;
  int* so = sog + (size_t)b * NPTS;
#pragma unroll
  for (int j = 0; j < 16; ++j) {
    const int n = t + (j << 10);
    const float x = X[n], y = Y[n], z = Z[n];
    const int pos = atomicAdd(&off[morton_cell(x, y, z)], 1);
    sx[pos] = x; sy[pos] = y; sz[pos] = z; so[pos] = n;
  }
}

// ---------------------------------------------------------------------------
// Kernel 1: bbox-pruned farthest point sampling. One block per batch, 1024
// threads = 16 waves; wave w owns sorted points [w*1024,(w+1)*1024) (compact
// Morton region). Per step: conservative skip test lb=clampdist(c,bbox)^2 *
// 0.9999 vs wave gmax — if lb>=gmax, NO point's dist can change (margin
// 1e-4 >> 2^-20 accumulated-RN slack), so the update is skipped bit-exactly.
// All argmax levels compare (value desc, orig-index asc) — order-invariant,
// identical to jnp.argmax first-occurrence. R7 learned: ~2.3 us/step is the
// full-update floor; pruning is the only way below it.
// ---------------------------------------------------------------------------
#define CH_LIST(F) \
  F(0)  F(1)  F(2)  F(3)  F(4)  F(5)  F(6)  F(7)  \
  F(8)  F(9)  F(10) F(11) F(12) F(13) F(14) F(15)

__global__ __launch_bounds__(1024)
void fps_kernel(const float* __restrict__ xyz, const float* __restrict__ sxg,
                const float* __restrict__ syg, const float* __restrict__ szg,
                const int* __restrict__ sog, int* __restrict__ fps_idx) {
  const int b = blockIdx.x;
  const int t = threadIdx.x;
  const int w = t >> 6, lane = t & 63;
  const float* X = xyz + (size_t)b * 3 * NPTS;
  const float* Y = X + NPTS;
  const float* Z = X + 2 * NPTS;
  const float* SX = sxg + (size_t)b * NPTS;
  const float* SY = syg + (size_t)b * NPTS;
  const float* SZ = szg + (size_t)b * NPTS;
  const int* SO = sog + (size_t)b * NPTS;

  __shared__ float sx[NPTS];  // 64 KB sorted x
  __shared__ float sy[NPTS];  // 64 KB sorted y
  __shared__ float s_v[32];   // [parity][16 waves]
  __shared__ int s_n[32];

#define DECL_CH(c) float z##c, d##c; int o##c;
  CH_LIST(DECL_CH)
#undef DECL_CH

  float mnx = __builtin_inff(), mxx = -__builtin_inff();
  float mny = __builtin_inff(), mxy = -__builtin_inff();
  float mnz = __builtin_inff(), mxz = -__builtin_inff();

#define INIT_CH(c)                                   \
  {                                                  \
    const int p = (w << 10) + (c << 6) + lane;       \
    const float xv = SX[p], yv = SY[p];              \
    sx[p] = xv; sy[p] = yv;                          \
    z##c = SZ[p]; o##c = SO[p];                      \
    d##c = __builtin_inff();                         \
    mnx = fminf(mnx, xv); mxx = fmaxf(mxx, xv);      \
    mny = fminf(mny, yv); mxy = fmaxf(mxy, yv);      \
    mnz = fminf(mnz, z##c); mxz = fmaxf(mxz, z##c);  \
  }
  CH_LIST(INIT_CH)
#undef INIT_CH

#define PIN_CH(c) asm volatile("" : "+v"(z##c), "+v"(o##c));
  CH_LIST(PIN_CH)
#undef PIN_CH

  // wave bbox via xor butterflies (all lanes end with the result)
#pragma unroll
  for (int off = 32; off >= 1; off >>= 1) {
    mnx = fminf(mnx, __shfl_xor(mnx, off));
    mxx = fmaxf(mxx, __shfl_xor(mxx, off));
    mny = fminf(mny, __shfl_xor(mny, off));
    mxy = fmaxf(mxy, __shfl_xor(mxy, off));
    mnz = fminf(mnz, __shfl_xor(mnz, off));
    mxz = fmaxf(mxz, __shfl_xor(mxz, off));
  }

  if (t == 0) fps_idx[b * NCTR] = 0;
  __syncthreads();  // LDS staging complete

  // first centroid = original point 0 (uniform loads from original layout)
  float cx = X[0], cy = Y[0], cz = Z[0];
  float gv = __builtin_inff();  // inf => "must update" on first step
  int gn = 0x7fffffff;

  for (int i = 1; i < NCTR; ++i) {
    // conservative skip test (wave-uniform)
    const float ux = fmaxf(fmaxf(__fsub_rn(mnx, cx), __fsub_rn(cx, mxx)), 0.0f);
    const float uy = fmaxf(fmaxf(__fsub_rn(mny, cy), __fsub_rn(cy, mxy)), 0.0f);
    const float uz = fmaxf(fmaxf(__fsub_rn(mnz, cz), __fsub_rn(cz, mxz)), 0.0f);
    const float lb = __fadd_rn(__fadd_rn(__fmul_rn(ux, ux), __fmul_rn(uy, uy)),
                               __fmul_rn(uz, uz));
    const float lb_safe = __fmul_rn(lb, 0.9999f);
    if (!(lb_safe >= gv)) {  // update needed (gv=inf forces first pass)
      float bv = -__builtin_inff();
      int bn = 0x7fffffff;
#define STEP_CH(c)                                                        \
  {                                                                       \
    const int p = (w << 10) + (c << 6) + lane;                            \
    const float dd = sq_dist(sx[p], sy[p], z##c, cx, cy, cz);             \
    d##c = fminf(d##c, dd);                                               \
    const bool better = (d##c > bv) || ((d##c == bv) & (o##c < bn));      \
    bv = better ? d##c : bv;                                              \
    bn = better ? o##c : bn;                                              \
  }
      CH_LIST(STEP_CH)
#undef STEP_CH
      // wave argmax butterfly: (value desc, orig asc), all lanes converge
#pragma unroll
      for (int off = 32; off >= 1; off >>= 1) {
        const float ov = __shfl_xor(bv, off);
        const int on = __shfl_xor(bn, off);
        const bool better = (ov > bv) || ((ov == bv) & (on < bn));
        bv = better ? ov : bv;
        bn = better ? on : bn;
      }
      gv = bv;
      gn = bn;
    }
    const int base = (i & 1) << 4;
    if (lane == 0) { s_v[base + w] = gv; s_n[base + w] = gn; }
    __syncthreads();  // the ONLY barrier per step

    // 16-slot mini-reduce, redundantly in every wave (lane0 correct)
    const int sl = base + (lane & 15);
    float v = s_v[sl];
    int n = s_n[sl];
#pragma unroll
    for (int off = 8; off >= 1; off >>= 1) {
      const float ov = __shfl_down(v, off);
      const int on = __shfl_down(n, off);
      const bool better = (ov > v) || ((ov == v) & (on < n));
      v = better ? ov : v;
      n = better ? on : n;
    }
    const int nu = __builtin_amdgcn_readfirstlane(n);  // orig index
    if (t == 0) fps_idx[b * NCTR + i] = nu;

    // centroid coords from ORIGINAL arrays (uniform L2 loads)
    cx = X[nu];
    cy = Y[nu];
    cz = Z[nu];
  }
}

// ---------------------------------------------------------------------------
// Kernel 2: ball query. One wave per centroid; scan points in ascending index
// order, collect first 32 with dist <= r^2, pad with first hit.
// ---------------------------------------------------------------------------
__global__ __launch_bounds__(256) void ballq_kernel(const float* __restrict__ xyz,
                                                    const int* __restrict__ fps_idx,
                                                    int* __restrict__ ball_idx) {
  const int gw = (blockIdx.x * 256 + threadIdx.x) >> 6;  // 0..8191
  const int lane = threadIdx.x & 63;
  const int b = gw >> 10;
  const float* X = xyz + (size_t)b * 3 * NPTS;
  const float* Y = X + NPTS;
  const float* Z = X + 2 * NPTS;
  const int c = fps_idx[gw];
  const float cx = X[c], cy = Y[c], cz = Z[c];
  int* out = ball_idx + (size_t)gw * 32;
  const float R2 = 0.04f;

  int cnt = 0, first = -1;
  for (int base = 0; base < NPTS; base += 64) {
    const int j = base + lane;
    const float d = sq_dist(X[j], Y[j], Z[j], cx, cy, cz);
    const bool inb = !(d > R2);
    const unsigned long long m = __ballot(inb);
    if (first < 0 && m != 0ull) first = base + __ffsll(m) - 1;
    if (inb) {
      const int pos = cnt + __popcll(m & ((1ull << lane) - 1ull));
      if (pos < 32) out[pos] = j;
    }
    cnt += __popcll(m);
    if (cnt >= 32) break;
  }
  for (int k = cnt + lane; k < 32; k += 64) out[k] = first;
}

// ---------------------------------------------------------------------------
// Kernel 2b: one-off weight transpose into workspace: wt[c][o] layouts.
// ---------------------------------------------------------------------------
__global__ __launch_bounds__(256) void transpose_w_kernel(
    const float* __restrict__ w0, const float* __restrict__ w1,
    const float* __restrict__ w2, float* __restrict__ wt0,
    float* __restrict__ wt1, float* __restrict__ wt2) {
  const int t0 = blockIdx.x * 256 + threadIdx.x;
  const int stride = gridDim.x * 256;
  for (int e = t0; e < 64 * 67; e += stride) {
    int o = e / 67, c = e - o * 67;
    wt0[c * 64 + o] = w0[e];
  }
  for (int e = t0; e < 128 * 64; e += stride) {
    int o = e >> 6, c = e & 63;
    wt1[c * 128 + o] = w1[e];
  }
  for (int e = t0; e < 256 * 128; e += stride) {
    int o = e >> 7, c = e & 127;
    wt2[c * 256 + o] = w2[e];
  }
}

// ---------------------------------------------------------------------------
// Kernel 3: fused gather + 3-layer pointwise MLP + mean over 32 samples.
// One block per (b, s) group, 256 threads. Activations LDS channel-major
// [c][36] (float4 over k); weights staged from pre-transposed wt* with
// stride-1 conflict-free LDS writes.
// ---------------------------------------------------------------------------
__global__ __launch_bounds__(256, 2) void mlp_kernel(
    const float* __restrict__ xyz, const float* __restrict__ points,
    const int* __restrict__ fps_idx, const int* __restrict__ ball_idx,
    const float* __restrict__ wt0, const float* __restrict__ b0,
    const float* __restrict__ wt1, const float* __restrict__ b1,
    const float* __restrict__ wt2, const float* __restrict__ b2,
    float* __restrict__ out) {
  const int s = blockIdx.x, b = blockIdx.y, t = threadIdx.x;

  __shared__ float A1[64 * 36];    // layer0 out [o][k]
  __shared__ float A2[128 * 36];   // layer1 out [o][k]
  __shared__ float S[8704];        // scratch: A0+Wt0 | Wt1 | Wt2 chunk
  __shared__ float bias_sh[256];
  __shared__ int jidx[32];
  __shared__ float ctr[3];

  const int g = b * NCTR + s;

  // phase 1: indices, centroid, Wt0 [67][68] (stride-1 writes), bias0
  if (t < 32) jidx[t] = ball_idx[(size_t)g * 32 + t];
  if (t < 3) ctr[t] = xyz[((size_t)b * 3 + t) * NPTS + fps_idx[g]];
  float* A0 = S;              // [67][36]
  float* Wt0 = S + 67 * 36;   // [67][68]
  for (int e = t; e < 67 * 64; e += 256) {
    int c = e >> 6, o = e & 63;
    Wt0[c * 68 + o] = wt0[e];  // global coalesced, LDS stride-1
  }
  if (t < 64) bias_sh[t] = b0[t];
  __syncthreads();

  // phase 2: gather A0 = [xyz_norm(3); points(64)] x 32 samples
  for (int e = t; e < 67 * 32; e += 256) {
    int c = e >> 5, k = e & 31;
    int j = jidx[k];
    float v;
    if (c < 3)
      v = xyz[((size_t)b * 3 + c) * NPTS + j] - ctr[c];
    else
      v = points[((size_t)b * 64 + (c - 3)) * NPTS + j];
    A0[c * 36 + k] = v;
  }
  __syncthreads();

  // phase 3: layer 0 (67 -> 64), tile 4k x 2o
  {
    const int o0 = (t & 31) * 2;
    const int k0 = (t >> 5) * 4;
    float acc[4][2] = {{0.f, 0.f}, {0.f, 0.f}, {0.f, 0.f}, {0.f, 0.f}};
    for (int c = 0; c < 67; ++c) {
      const float4 a = *(const float4*)(A0 + c * 36 + k0);
      const float wv0 = Wt0[c * 68 + o0];
      const float wv1 = Wt0[c * 68 + o0 + 1];
      acc[0][0] = fmaf(a.x, wv0, acc[0][0]);
      acc[1][0] = fmaf(a.y, wv0, acc[1][0]);
      acc[2][0] = fmaf(a.z, wv0, acc[2][0]);
      acc[3][0] = fmaf(a.w, wv0, acc[3][0]);
      acc[0][1] = fmaf(a.x, wv1, acc[0][1]);
      acc[1][1] = fmaf(a.y, wv1, acc[1][1]);
      acc[2][1] = fmaf(a.z, wv1, acc[2][1]);
      acc[3][1] = fmaf(a.w, wv1, acc[3][1]);
    }
#pragma unroll
    for (int i = 0; i < 2; ++i) {
      const float bb = bias_sh[o0 + i];
      float4 r;
      r.x = silu_f(acc[0][i] + bb);
      r.y = silu_f(acc[1][i] + bb);
      r.z = silu_f(acc[2][i] + bb);
      r.w = silu_f(acc[3][i] + bb);
      *(float4*)(A1 + (o0 + i) * 36 + k0) = r;
    }
  }
  __syncthreads();

  // phase 4: stage Wt1 [64][132] (stride-1 writes), bias1
  float* Wt1 = S;
  for (int e = t; e < 128 * 64; e += 256) {
    int c = e >> 7, o = e & 127;
    Wt1[c * 132 + o] = wt1[e];
  }
  if (t < 128) bias_sh[t] = b1[t];
  __syncthreads();

  // phase 5: layer 1 (64 -> 128), tile 4k x 4o
  {
    const int o0 = (t & 31) * 4;
    const int k0 = (t >> 5) * 4;
    float acc[4][4];
#pragma unroll
    for (int kk = 0; kk < 4; ++kk)
#pragma unroll
      for (int oo = 0; oo < 4; ++oo) acc[kk][oo] = 0.f;
    for (int c = 0; c < 64; ++c) {
      const float4 a = *(const float4*)(A1 + c * 36 + k0);
      const float4 w = *(const float4*)(Wt1 + c * 132 + o0);
      const float av[4] = {a.x, a.y, a.z, a.w};
      const float wv[4] = {w.x, w.y, w.z, w.w};
#pragma unroll
      for (int kk = 0; kk < 4; ++kk)
#pragma unroll
        for (int oo = 0; oo < 4; ++oo)
          acc[kk][oo] = fmaf(av[kk], wv[oo], acc[kk][oo]);
    }
#pragma unroll
    for (int oo = 0; oo < 4; ++oo) {
      const float bb = bias_sh[o0 + oo];
      float4 r;
      r.x = silu_f(acc[0][oo] + bb);
      r.y = silu_f(acc[1][oo] + bb);
      r.z = silu_f(acc[2][oo] + bb);
      r.w = silu_f(acc[3][oo] + bb);
      *(float4*)(A2 + (o0 + oo) * 36 + k0) = r;
    }
  }
  __syncthreads();

  // phase 6: layer 2 (128 -> 256) in 4 chunks of 64 outputs + mean over k
  float* Wt2 = S;   // [128][68] per chunk
  float* P = A1;    // partial sums [64][9] (A1 dead)
  const int o0 = (t & 31) * 2;
  const int k0 = (t >> 5) * 4;
  const int kg = t >> 5;
  for (int chunk = 0; chunk < 4; ++chunk) {
    for (int e = t; e < 64 * 128; e += 256) {
      int c = e >> 6, o = e & 63;
      Wt2[c * 68 + o] = wt2[c * 256 + chunk * 64 + o];  // coalesced / stride-1
    }
    if (t < 64) bias_sh[t] = b2[chunk * 64 + t];
    __syncthreads();

    float acc[4][2] = {{0.f, 0.f}, {0.f, 0.f}, {0.f, 0.f}, {0.f, 0.f}};
    for (int c = 0; c < 128; ++c) {
      const float4 a = *(const float4*)(A2 + c * 36 + k0);
      const float wv0 = Wt2[c * 68 + o0];
      const float wv1 = Wt2[c * 68 + o0 + 1];
      acc[0][0] = fmaf(a.x, wv0, acc[0][0]);
      acc[1][0] = fmaf(a.y, wv0, acc[1][0]);
      acc[2][0] = fmaf(a.z, wv0, acc[2][0]);
      acc[3][0] = fmaf(a.w, wv0, acc[3][0]);
      acc[0][1] = fmaf(a.x, wv1, acc[0][1]);
      acc[1][1] = fmaf(a.y, wv1, acc[1][1]);
      acc[2][1] = fmaf(a.z, wv1, acc[2][1]);
      acc[3][1] = fmaf(a.w, wv1, acc[3][1]);
    }
#pragma unroll
    for (int i = 0; i < 2; ++i) {
      const float bb = bias_sh[o0 + i];
      float sum = silu_f(acc[0][i] + bb) + silu_f(acc[1][i] + bb) +
                  silu_f(acc[2][i] + bb) + silu_f(acc[3][i] + bb);
      P[(o0 + i) * 9 + kg] = sum;
    }
    __syncthreads();
    if (t < 64) {
      float tot = 0.f;
#pragma unroll
      for (int q = 0; q < 8; ++q) tot += P[t * 9 + q];
      out[((size_t)b * 256 + chunk * 64 + t) * NCTR + s] = tot * (1.0f / 32.0f);
    }
    __syncthreads();
  }
}

extern "C" void kernel_launch(void* const* d_in, const int* in_sizes, int n_in,
                              void* d_out, int out_size, void* d_ws, size_t ws_size,
                              hipStream_t stream) {
  const float* xyz = (const float*)d_in[0];
  const float* points = (const float*)d_in[1];
  const float* w0 = (const float*)d_in[2];
  const float* b0 = (const float*)d_in[3];
  const float* w1 = (const float*)d_in[4];
  const float* b1 = (const float*)d_in[5];
  const float* w2 = (const float*)d_in[6];
  const float* b2 = (const float*)d_in[7];
  float* out = (float*)d_out;

  int* fps = (int*)d_ws;                       // 8K ints
  int* bidx = (int*)d_ws + 8192;               // 256K ints
  float* wt0 = (float*)d_ws + 270336;          // 67*64
  float* wt1 = wt0 + 67 * 64;                  // 64*128
  float* wt2 = wt1 + 64 * 128;                 // 128*256
  float* sxg = (float*)d_ws + 315584;          // 8*16384 sorted x
  float* syg = sxg + BATCH * NPTS;             // sorted y
  float* szg = syg + BATCH * NPTS;             // sorted z
  int* sog = (int*)(szg + BATCH * NPTS);       // sorted orig idx (~3.4 MB total)

  transpose_w_kernel<<<64, 256, 0, stream>>>(w0, w1, w2, wt0, wt1, wt2);
  sort_kernel<<<BATCH, 1024, 0, stream>>>(xyz, sxg, syg, szg, sog);
  fps_kernel<<<BATCH, 1024, 0, stream>>>(xyz, sxg, syg, szg, sog, fps);
  ballq_kernel<<<2048, 256, 0, stream>>>(xyz, fps, bidx);
  mlp_kernel<<<dim3(NCTR, BATCH), 256, 0, stream>>>(xyz, points, fps, bidx,
                                                    wt0, b0, wt1, b1, wt2, b2, out);
}

// Round 10
// 2316.031 us; speedup vs baseline: 1.5765x; 1.2802x over previous
//
#include <hip/hip_runtime.h>
#include <math.h>

#define NPTS 16384
#define NCTR 1024
#define BATCH 8
#define NCELL 512  // 8x8x8 Morton cells

typedef unsigned long long u64;
typedef unsigned int u32;

// Bit-exact squared distance matching numpy: ((dx*dx + dy*dy) + dz*dz),
// each op individually IEEE-rounded (no FMA contraction).
__device__ __forceinline__ float sq_dist(float x, float y, float z,
                                         float cx, float cy, float cz) {
  float dx = __fsub_rn(x, cx);
  float dy = __fsub_rn(y, cy);
  float dz = __fsub_rn(z, cz);
  return __fadd_rn(__fadd_rn(__fmul_rn(dx, dx), __fmul_rn(dy, dy)), __fmul_rn(dz, dz));
}

__device__ __forceinline__ float silu_f(float x) {
  return x / (1.0f + __expf(-x));
}

__device__ __forceinline__ u64 kmax(u64 a, u64 b) { return a > b ? a : b; }

__device__ __forceinline__ int morton_cell(float x, float y, float z) {
  int mx = min(7, max(0, (int)(x * 8.0f)));
  int my = min(7, max(0, (int)(y * 8.0f)));
  int mz = min(7, max(0, (int)(z * 8.0f)));
  int m = 0;
#pragma unroll
  for (int k = 0; k < 3; ++k) {
    m |= ((mx >> k) & 1) << (3 * k + 2);
    m |= ((my >> k) & 1) << (3 * k + 1);
    m |= ((mz >> k) & 1) << (3 * k + 0);
  }
  return m;
}

// ---------------------------------------------------------------------------
// Kernel 0: DETERMINISTIC Morton counting sort, one block per batch.
// R9 post-mortem: first call passed, a timed replay diverged — the only
// nondeterminism in the pipeline was this kernel's atomic scatter order.
// Fix: (A) racy scatter of orig-index into LDS (the per-cell SET is
// deterministic), (B) per-cell insertion sort by orig index (1 thread/cell,
// LDS), (C) rebuild x/y/z/so deterministically. Downstream kernels have no
// atomics, so every launch is now bit-identical.
// ---------------------------------------------------------------------------
__global__ __launch_bounds__(1024) void sort_kernel(
    const float* __restrict__ xyz, float* __restrict__ sxg,
    float* __restrict__ syg, float* __restrict__ szg, int* __restrict__ sog) {
  const int b = blockIdx.x, t = threadIdx.x;
  const float* X = xyz + (size_t)b * 3 * NPTS;
  const float* Y = X + NPTS;
  const float* Z = X + 2 * NPTS;
  __shared__ int cnt[NCELL];
  __shared__ int off[NCELL];
  __shared__ int start[NCELL];
  __shared__ int so_l[NPTS];  // 64 KB
  for (int e = t; e < NCELL; e += 1024) cnt[e] = 0;
  __syncthreads();
#pragma unroll
  for (int j = 0; j < 16; ++j) {
    const int n = t + (j << 10);
    atomicAdd(&cnt[morton_cell(X[n], Y[n], Z[n])], 1);
  }
  __syncthreads();
  if (t < NCELL) off[t] = cnt[t];
  __syncthreads();
  for (int d = 1; d < NCELL; d <<= 1) {  // Hillis-Steele inclusive scan
    int v = 0;
    if (t < NCELL) { v = off[t]; if (t >= d) v += off[t - d]; }
    __syncthreads();
    if (t < NCELL) off[t] = v;
    __syncthreads();
  }
  if (t < NCELL) { off[t] -= cnt[t]; start[t] = off[t]; }
  __syncthreads();
  // phase A: racy scatter of orig index (intra-cell order arbitrary)
#pragma unroll
  for (int j = 0; j < 16; ++j) {
    const int n = t + (j << 10);
    const int pos = atomicAdd(&off[morton_cell(X[n], Y[n], Z[n])], 1);
    so_l[pos] = n;
  }
  __syncthreads();
  // phase B: deterministic intra-cell order (ascending orig index)
  if (t < NCELL) {
    const int s0 = start[t], k = cnt[t];
    for (int i2 = 1; i2 < k; ++i2) {
      const int key = so_l[s0 + i2];
      int j2 = i2 - 1;
      while (j2 >= 0 && so_l[s0 + j2] > key) {
        so_l[s0 + j2 + 1] = so_l[s0 + j2];
        --j2;
      }
      so_l[s0 + j2 + 1] = key;
    }
  }
  __syncthreads();
  // phase C: deterministic rebuild
  float* sx = sxg + (size_t)b * NPTS;
  float* sy = syg + (size_t)b * NPTS;
  float* sz = szg + (size_t)b * NPTS;
  int* so = sog + (size_t)b * NPTS;
#pragma unroll
  for (int j = 0; j < 16; ++j) {
    const int pos = t + (j << 10);
    const int n = so_l[pos];
    so[pos] = n;
    sx[pos] = X[n];
    sy[pos] = Y[n];
    sz[pos] = Z[n];
  }
}

// ---------------------------------------------------------------------------
// Kernel 1: latency-optimized bbox-pruned FPS (R9 structure, validated on
// first-call correctness; now fed deterministic sorted input).
//  - u64 argmax key (dist_bits<<32)|((16383-n)<<14)|p : max() == (dist desc,
//    orig-n asc); winner's sorted pos p rides along -> centroid from ONE
//    ds_read_b64 (sxy interleaved in LDS) + ONE uniform load (sorted z).
//  - butterfly/scan carry one u64; block reduce = 16 broadcast b64 reads.
//  - in-lane argmax via 4 interleaved accumulators (dep-depth 4).
//  - wave-level bbox skip test: provably bit-exact no-op elision (monotone
//    rounding argument + 0.9999 margin).
// Keys unique (orig n unique) => ties resolve exactly as jnp.argmax.
// ---------------------------------------------------------------------------
#define CH_LIST(F) \
  F(0,a0)  F(1,a1)  F(2,a2)  F(3,a3)  F(4,a0)  F(5,a1)  F(6,a2)  F(7,a3)  \
  F(8,a0)  F(9,a1)  F(10,a2) F(11,a3) F(12,a0) F(13,a1) F(14,a2) F(15,a3)

__global__ __launch_bounds__(1024)
void fps_kernel(const float* __restrict__ xyz, const float* __restrict__ sxg,
                const float* __restrict__ syg, const float* __restrict__ szg,
                const int* __restrict__ sog, int* __restrict__ fps_idx) {
  const int b = blockIdx.x;
  const int t = threadIdx.x;
  const int w = t >> 6, lane = t & 63;
  const float* X = xyz + (size_t)b * 3 * NPTS;
  const float* Y = X + NPTS;
  const float* Z = X + 2 * NPTS;
  const float* SX = sxg + (size_t)b * NPTS;
  const float* SY = syg + (size_t)b * NPTS;
  const float* SZ = szg + (size_t)b * NPTS;
  const int* SO = sog + (size_t)b * NPTS;

  __shared__ float sxy[2 * NPTS];  // 128 KB interleaved sorted x,y
  __shared__ u64 s_key[32];        // [parity][16 waves]

#define DECL_CH(c, acc) float z##c, d##c; u32 lo##c;
  CH_LIST(DECL_CH)
#undef DECL_CH

  float mnx = __builtin_inff(), mxx = -__builtin_inff();
  float mny = __builtin_inff(), mxy = -__builtin_inff();
  float mnz = __builtin_inff(), mxz = -__builtin_inff();

#define INIT_CH(c, acc)                                  \
  {                                                      \
    const int p = (w << 10) + (c << 6) + lane;           \
    const float xv = SX[p], yv = SY[p];                  \
    sxy[2 * p] = xv; sxy[2 * p + 1] = yv;                \
    z##c = SZ[p];                                        \
    const int o = SO[p];                                 \
    lo##c = ((u32)(16383 - o) << 14) | (u32)p;           \
    d##c = __builtin_inff();                             \
    mnx = fminf(mnx, xv); mxx = fmaxf(mxx, xv);          \
    mny = fminf(mny, yv); mxy = fmaxf(mxy, yv);          \
    mnz = fminf(mnz, z##c); mxz = fmaxf(mxz, z##c);      \
  }
  CH_LIST(INIT_CH)
#undef INIT_CH

#define PIN_CH(c, acc) asm volatile("" : "+v"(z##c), "+v"(lo##c));
  CH_LIST(PIN_CH)
#undef PIN_CH

  // wave bbox via xor butterflies (all lanes converge)
#pragma unroll
  for (int off = 32; off >= 1; off >>= 1) {
    mnx = fminf(mnx, __shfl_xor(mnx, off));
    mxx = fmaxf(mxx, __shfl_xor(mxx, off));
    mny = fminf(mny, __shfl_xor(mny, off));
    mxy = fmaxf(mxy, __shfl_xor(mxy, off));
    mnz = fminf(mnz, __shfl_xor(mnz, off));
    mxz = fmaxf(mxz, __shfl_xor(mxz, off));
  }

  if (t == 0) fps_idx[b * NCTR] = 0;
  __syncthreads();  // LDS staging complete

  // first centroid = original point 0 (uniform loads)
  float cx = X[0], cy = Y[0], cz = Z[0];
  u64 gkey = ((u64)0x7F800000u << 32);  // v=+inf => forces update at i=1

  for (int i = 1; i < NCTR; ++i) {
    // conservative wave-level skip test (bit-exact no-op elision)
    const float gv = __uint_as_float((u32)(gkey >> 32));
    const float ux = fmaxf(fmaxf(__fsub_rn(mnx, cx), __fsub_rn(cx, mxx)), 0.0f);
    const float uy = fmaxf(fmaxf(__fsub_rn(mny, cy), __fsub_rn(cy, mxy)), 0.0f);
    const float uz = fmaxf(fmaxf(__fsub_rn(mnz, cz), __fsub_rn(cz, mxz)), 0.0f);
    const float lb = __fadd_rn(__fadd_rn(__fmul_rn(ux, ux), __fmul_rn(uy, uy)),
                               __fmul_rn(uz, uz));
    if (!(__fmul_rn(lb, 0.9999f) >= gv)) {
      u64 a0 = 0, a1 = 0, a2 = 0, a3 = 0;  // 4 accumulators: dep-depth 4
#define STEP_CH(c, acc)                                                \
  {                                                                    \
    const int p = (w << 10) + (c << 6) + lane;                         \
    const float2 xy = *(const float2*)(sxy + 2 * p);                   \
    const float dd = sq_dist(xy.x, xy.y, z##c, cx, cy, cz);            \
    d##c = fminf(d##c, dd);                                            \
    const u64 k = ((u64)__float_as_uint(d##c) << 32) | (u64)lo##c;     \
    acc = kmax(acc, k);                                                \
  }
      CH_LIST(STEP_CH)
#undef STEP_CH
      u64 k = kmax(kmax(a0, a1), kmax(a2, a3));
      // wave argmax butterfly over u64 keys
#pragma unroll
      for (int off = 32; off >= 1; off >>= 1)
        k = kmax(k, __shfl_xor(k, off));
      gkey = k;
    }
    const int base = (i & 1) << 4;
    if (lane == 0) s_key[base + w] = gkey;
    __syncthreads();  // the ONLY barrier per step

    // block reduce: 16 broadcast b64 reads + 15 u64-max (all lanes converge)
    u64 m = s_key[base + 0];
#pragma unroll
    for (int q = 1; q < 16; ++q) m = kmax(m, s_key[base + q]);

    const u32 lowb = (u32)m;
    const int pw = (int)(lowb & 0x3FFFu);  // winner's sorted position
    if (t == 0) fps_idx[b * NCTR + i] = 16383 - (int)((lowb >> 14) & 0x3FFFu);

    const int pu = __builtin_amdgcn_readfirstlane(pw);
    const float2 cxy = *(const float2*)(sxy + 2 * pu);  // one ds_read_b64
    cx = cxy.x;
    cy = cxy.y;
    cz = SZ[pu];  // one uniform load (L2-warm sorted z)
  }
}

// ---------------------------------------------------------------------------
// Kernel 2: ball query. One wave per centroid; scan points in ascending index
// order, collect first 32 with dist <= r^2, pad with first hit.
// ---------------------------------------------------------------------------
__global__ __launch_bounds__(256) void ballq_kernel(const float* __restrict__ xyz,
                                                    const int* __restrict__ fps_idx,
                                                    int* __restrict__ ball_idx) {
  const int gw = (blockIdx.x * 256 + threadIdx.x) >> 6;  // 0..8191
  const int lane = threadIdx.x & 63;
  const int b = gw >> 10;
  const float* X = xyz + (size_t)b * 3 * NPTS;
  const float* Y = X + NPTS;
  const float* Z = X + 2 * NPTS;
  const int c = fps_idx[gw];
  const float cx = X[c], cy = Y[c], cz = Z[c];
  int* out = ball_idx + (size_t)gw * 32;
  const float R2 = 0.04f;

  int cnt = 0, first = -1;
  for (int base = 0; base < NPTS; base += 64) {
    const int j = base + lane;
    const float d = sq_dist(X[j], Y[j], Z[j], cx, cy, cz);
    const bool inb = !(d > R2);
    const unsigned long long m = __ballot(inb);
    if (first < 0 && m != 0ull) first = base + __ffsll(m) - 1;
    if (inb) {
      const int pos = cnt + __popcll(m & ((1ull << lane) - 1ull));
      if (pos < 32) out[pos] = j;
    }
    cnt += __popcll(m);
    if (cnt >= 32) break;
  }
  for (int k = cnt + lane; k < 32; k += 64) out[k] = first;
}

// ---------------------------------------------------------------------------
// Kernel 2b: one-off weight transpose into workspace: wt[c][o] layouts.
// ---------------------------------------------------------------------------
__global__ __launch_bounds__(256) void transpose_w_kernel(
    const float* __restrict__ w0, const float* __restrict__ w1,
    const float* __restrict__ w2, float* __restrict__ wt0,
    float* __restrict__ wt1, float* __restrict__ wt2) {
  const int t0 = blockIdx.x * 256 + threadIdx.x;
  const int stride = gridDim.x * 256;
  for (int e = t0; e < 64 * 67; e += stride) {
    int o = e / 67, c = e - o * 67;
    wt0[c * 64 + o] = w0[e];
  }
  for (int e = t0; e < 128 * 64; e += stride) {
    int o = e >> 6, c = e & 63;
    wt1[c * 128 + o] = w1[e];
  }
  for (int e = t0; e < 256 * 128; e += stride) {
    int o = e >> 7, c = e & 127;
    wt2[c * 256 + o] = w2[e];
  }
}

// ---------------------------------------------------------------------------
// Kernel 3: fused gather + 3-layer pointwise MLP + mean over 32 samples.
// One block per (b, s) group, 256 threads. Activations LDS channel-major
// [c][36] (float4 over k); weights staged from pre-transposed wt* with
// stride-1 conflict-free LDS writes.
// ---------------------------------------------------------------------------
__global__ __launch_bounds__(256, 2) void mlp_kernel(
    const float* __restrict__ xyz, const float* __restrict__ points,
    const int* __restrict__ fps_idx, const int* __restrict__ ball_idx,
    const float* __restrict__ wt0, const float* __restrict__ b0,
    const float* __restrict__ wt1, const float* __restrict__ b1,
    const float* __restrict__ wt2, const float* __restrict__ b2,
    float* __restrict__ out) {
  const int s = blockIdx.x, b = blockIdx.y, t = threadIdx.x;

  __shared__ float A1[64 * 36];    // layer0 out [o][k]
  __shared__ float A2[128 * 36];   // layer1 out [o][k]
  __shared__ float S[8704];        // scratch: A0+Wt0 | Wt1 | Wt2 chunk
  __shared__ float bias_sh[256];
  __shared__ int jidx[32];
  __shared__ float ctr[3];

  const int g = b * NCTR + s;

  // phase 1: indices, centroid, Wt0 [67][68] (stride-1 writes), bias0
  if (t < 32) jidx[t] = ball_idx[(size_t)g * 32 + t];
  if (t < 3) ctr[t] = xyz[((size_t)b * 3 + t) * NPTS + fps_idx[g]];
  float* A0 = S;              // [67][36]
  float* Wt0 = S + 67 * 36;   // [67][68]
  for (int e = t; e < 67 * 64; e += 256) {
    int c = e >> 6, o = e & 63;
    Wt0[c * 68 + o] = wt0[e];  // global coalesced, LDS stride-1
  }
  if (t < 64) bias_sh[t] = b0[t];
  __syncthreads();

  // phase 2: gather A0 = [xyz_norm(3); points(64)] x 32 samples
  for (int e = t; e < 67 * 32; e += 256) {
    int c = e >> 5, k = e & 31;
    int j = jidx[k];
    float v;
    if (c < 3)
      v = xyz[((size_t)b * 3 + c) * NPTS + j] - ctr[c];
    else
      v = points[((size_t)b * 64 + (c - 3)) * NPTS + j];
    A0[c * 36 + k] = v;
  }
  __syncthreads();

  // phase 3: layer 0 (67 -> 64), tile 4k x 2o
  {
    const int o0 = (t & 31) * 2;
    const int k0 = (t >> 5) * 4;
    float acc[4][2] = {{0.f, 0.f}, {0.f, 0.f}, {0.f, 0.f}, {0.f, 0.f}};
    for (int c = 0; c < 67; ++c) {
      const float4 a = *(const float4*)(A0 + c * 36 + k0);
      const float wv0 = Wt0[c * 68 + o0];
      const float wv1 = Wt0[c * 68 + o0 + 1];
      acc[0][0] = fmaf(a.x, wv0, acc[0][0]);
      acc[1][0] = fmaf(a.y, wv0, acc[1][0]);
      acc[2][0] = fmaf(a.z, wv0, acc[2][0]);
      acc[3][0] = fmaf(a.w, wv0, acc[3][0]);
      acc[0][1] = fmaf(a.x, wv1, acc[0][1]);
      acc[1][1] = fmaf(a.y, wv1, acc[1][1]);
      acc[2][1] = fmaf(a.z, wv1, acc[2][1]);
      acc[3][1] = fmaf(a.w, wv1, acc[3][1]);
    }
#pragma unroll
    for (int i = 0; i < 2; ++i) {
      const float bb = bias_sh[o0 + i];
      float4 r;
      r.x = silu_f(acc[0][i] + bb);
      r.y = silu_f(acc[1][i] + bb);
      r.z = silu_f(acc[2][i] + bb);
      r.w = silu_f(acc[3][i] + bb);
      *(float4*)(A1 + (o0 + i) * 36 + k0) = r;
    }
  }
  __syncthreads();

  // phase 4: stage Wt1 [64][132] (stride-1 writes), bias1
  float* Wt1 = S;
  for (int e = t; e < 128 * 64; e += 256) {
    int c = e >> 7, o = e & 127;
    Wt1[c * 132 + o] = wt1[e];
  }
  if (t < 128) bias_sh[t] = b1[t];
  __syncthreads();

  // phase 5: layer 1 (64 -> 128), tile 4k x 4o
  {
    const int o0 = (t & 31) * 4;
    const int k0 = (t >> 5) * 4;
    float acc[4][4];
#pragma unroll
    for (int kk = 0; kk < 4; ++kk)
#pragma unroll
      for (int oo = 0; oo < 4; ++oo) acc[kk][oo] = 0.f;
    for (int c = 0; c < 64; ++c) {
      const float4 a = *(const float4*)(A1 + c * 36 + k0);
      const float4 w = *(const float4*)(Wt1 + c * 132 + o0);
      const float av[4] = {a.x, a.y, a.z, a.w};
      const float wv[4] = {w.x, w.y, w.z, w.w};
#pragma unroll
      for (int kk = 0; kk < 4; ++kk)
#pragma unroll
        for (int oo = 0; oo < 4; ++oo)
          acc[kk][oo] = fmaf(av[kk], wv[oo], acc[kk][oo]);
    }
#pragma unroll
    for (int oo = 0; oo < 4; ++oo) {
      const float bb = bias_sh[o0 + oo];
      float4 r;
      r.x = silu_f(acc[0][oo] + bb);
      r.y = silu_f(acc[1][oo] + bb);
      r.z = silu_f(acc[2][oo] + bb);
      r.w = silu_f(acc[3][oo] + bb);
      *(float4*)(A2 + (o0 + oo) * 36 + k0) = r;
    }
  }
  __syncthreads();

  // phase 6: layer 2 (128 -> 256) in 4 chunks of 64 outputs + mean over k
  float* Wt2 = S;   // [128][68] per chunk
  float* P = A1;    // partial sums [64][9] (A1 dead)
  const int o0 = (t & 31) * 2;
  const int k0 = (t >> 5) * 4;
  const int kg = t >> 5;
  for (int chunk = 0; chunk < 4; ++chunk) {
    for (int e = t; e < 64 * 128; e += 256) {
      int c = e >> 6, o = e & 63;
      Wt2[c * 68 + o] = wt2[c * 256 + chunk * 64 + o];  // coalesced / stride-1
    }
    if (t < 64) bias_sh[t] = b2[chunk * 64 + t];
    __syncthreads();

    float acc[4][2] = {{0.f, 0.f}, {0.f, 0.f}, {0.f, 0.f}, {0.f, 0.f}};
    for (int c = 0; c < 128; ++c) {
      const float4 a = *(const float4*)(A2 + c * 36 + k0);
      const float wv0 = Wt2[c * 68 + o0];
      const float wv1 = Wt2[c * 68 + o0 + 1];
      acc[0][0] = fmaf(a.x, wv0, acc[0][0]);
      acc[1][0] = fmaf(a.y, wv0, acc[1][0]);
      acc[2][0] = fmaf(a.z, wv0, acc[2][0]);
      acc[3][0] = fmaf(a.w, wv0, acc[3][0]);
      acc[0][1] = fmaf(a.x, wv1, acc[0][1]);
      acc[1][1] = fmaf(a.y, wv1, acc[1][1]);
      acc[2][1] = fmaf(a.z, wv1, acc[2][1]);
      acc[3][1] = fmaf(a.w, wv1, acc[3][1]);
    }
#pragma unroll
    for (int i = 0; i < 2; ++i) {
      const float bb = bias_sh[o0 + i];
      float sum = silu_f(acc[0][i] + bb) + silu_f(acc[1][i] + bb) +
                  silu_f(acc[2][i] + bb) + silu_f(acc[3][i] + bb);
      P[(o0 + i) * 9 + kg] = sum;
    }
    __syncthreads();
    if (t < 64) {
      float tot = 0.f;
#pragma unroll
      for (int q = 0; q < 8; ++q) tot += P[t * 9 + q];
      out[((size_t)b * 256 + chunk * 64 + t) * NCTR + s] = tot * (1.0f / 32.0f);
    }
    __syncthreads();
  }
}

extern "C" void kernel_launch(void* const* d_in, const int* in_sizes, int n_in,
                              void* d_out, int out_size, void* d_ws, size_t ws_size,
                              hipStream_t stream) {
  const float* xyz = (const float*)d_in[0];
  const float* points = (const float*)d_in[1];
  const float* w0 = (const float*)d_in[2];
  const float* b0 = (const float*)d_in[3];
  const float* w1 = (const float*)d_in[4];
  const float* b1 = (const float*)d_in[5];
  const float* w2 = (const float*)d_in[6];
  const float* b2 = (const float*)d_in[7];
  float* out = (float*)d_out;

  int* fps = (int*)d_ws;                       // 8K ints
  int* bidx = (int*)d_ws + 8192;               // 256K ints
  float* wt0 = (float*)d_ws + 270336;          // 67*64
  float* wt1 = wt0 + 67 * 64;                  // 64*128
  float* wt2 = wt1 + 64 * 128;                 // 128*256
  float* sxg = (float*)d_ws + 315584;          // 8*16384 sorted x
  float* syg = sxg + BATCH * NPTS;             // sorted y
  float* szg = syg + BATCH * NPTS;             // sorted z
  int* sog = (int*)(szg + BATCH * NPTS);       // sorted orig idx (~3.4 MB total)

  transpose_w_kernel<<<64, 256, 0, stream>>>(w0, w1, w2, wt0, wt1, wt2);
  sort_kernel<<<BATCH, 1024, 0, stream>>>(xyz, sxg, syg, szg, sog);
  fps_kernel<<<BATCH, 1024, 0, stream>>>(xyz, sxg, syg, szg, sog, fps);
  ballq_kernel<<<2048, 256, 0, stream>>>(xyz, fps, bidx);
  mlp_kernel<<<dim3(NCTR, BATCH), 256, 0, stream>>>(xyz, points, fps, bidx,
                                                    wt0, b0, wt1, b1, wt2, b2, out);
}